// Round 2
// baseline (214.151 us; speedup 1.0000x reference)
//
#include <hip/hip_runtime.h>
#include <hip/hip_bf16.h>

#define B_    128
#define N_    196
#define HDIM  512
#define VDIM  2048
#define ATT   512
#define M_TOT (B_ * N_)   // 25088

#define BM  128    // rows per GEMM block
#define BKK 64     // K step
#define BN  128    // ATT cols per GEMM block (4 chunks)

typedef float  f32x4  __attribute__((ext_vector_type(4)));
typedef __bf16 bf16x8 __attribute__((ext_vector_type(8)));
typedef __bf16 bf16x4 __attribute__((ext_vector_type(4)));

__device__ __forceinline__ void gload_lds16(const void* g, void* l) {
    __builtin_amdgcn_global_load_lds(
        (const __attribute__((address_space(1))) void*)g,
        (__attribute__((address_space(3))) void*)l, 16, 0, 0);
}

__device__ __forceinline__ float fast_tanh(float x) {
    float ax = fabsf(x);
    float e  = __expf(-2.f * ax);          // in (0,1], no overflow
    float t  = (1.f - e) / (1.f + e);
    return copysignf(t, x);
}

// ---------------------------------------------------------------------------
// Kernel CV: V fp32 -> bf16 (streaming, 8 elems/thread/iter)
// ---------------------------------------------------------------------------
__global__ void k_conv(const float* __restrict__ V, __bf16* __restrict__ Vb, int n8) {
    int idx    = blockIdx.x * blockDim.x + threadIdx.x;
    int stride = gridDim.x * blockDim.x;
    for (int i = idx; i < n8; i += stride) {
        const float4* s = reinterpret_cast<const float4*>(V + (size_t)i * 8);
        float4 x = s[0], y = s[1];
        bf16x8 w;
        w[0] = (__bf16)x.x; w[1] = (__bf16)x.y; w[2] = (__bf16)x.z; w[3] = (__bf16)x.w;
        w[4] = (__bf16)y.x; w[5] = (__bf16)y.y; w[6] = (__bf16)y.z; w[7] = (__bf16)y.w;
        reinterpret_cast<bf16x8*>(Vb)[i] = w;
    }
}

// ---------------------------------------------------------------------------
// Kernel T: Uw [VDIM][ATT] f32  ->  UwT [ATT][VDIM] bf16  (tiled transpose)
// ---------------------------------------------------------------------------
__global__ void k_transpose(const float* __restrict__ Uw, __bf16* __restrict__ UwT) {
    __shared__ __bf16 st[64][65];
    int k0 = blockIdx.x * 64;
    int c0 = blockIdx.y * 64;
    int t  = threadIdx.x;  // 256
#pragma unroll
    for (int i = 0; i < 16; ++i) {
        int lin = i * 256 + t;
        int kk = lin >> 6, cc = lin & 63;
        st[kk][cc] = (__bf16)Uw[(size_t)(k0 + kk) * ATT + c0 + cc];
    }
    __syncthreads();
#pragma unroll
    for (int i = 0; i < 16; ++i) {
        int lin = i * 256 + t;
        int cc = lin >> 6, kk = lin & 63;
        UwT[(size_t)(c0 + cc) * VDIM + k0 + kk] = st[kk][cc];
    }
}

// ---------------------------------------------------------------------------
// Kernel W: whp[b][a] = h[b] @ Ww[:,a] + Wb[a] + Ub[a]   (fp32, tiny)
// ---------------------------------------------------------------------------
__global__ void k_wh(const float* __restrict__ h, const float* __restrict__ Ww,
                     const float* __restrict__ Wb, const float* __restrict__ Ub,
                     float* __restrict__ whp) {
    __shared__ float hs[HDIM];
    int b = blockIdx.x;
    int t = threadIdx.x;  // 256
    hs[t]       = h[(size_t)b * HDIM + t];
    hs[t + 256] = h[(size_t)b * HDIM + t + 256];
    __syncthreads();
    float acc0 = 0.f, acc1 = 0.f;
    for (int k = 0; k < HDIM; ++k) {
        float hv = hs[k];
        acc0 += hv * Ww[(size_t)k * ATT + t];
        acc1 += hv * Ww[(size_t)k * ATT + t + 256];
    }
    whp[(size_t)b * ATT + t]       = acc0 + Wb[t] + Ub[t];
    whp[(size_t)b * ATT + t + 256] = acc1 + Wb[t + 256] + Ub[t + 256];
}

// ---------------------------------------------------------------------------
// Kernel G: m97-style 128x128 tile, BK=64, 4 waves, global_load_lds staging.
// Epilogue: e_part[cc][m] = sum_cols tanh(acc + whp) * vw
// PRECONV=true : A operand from bf16 Vb via global_load_lds
// PRECONV=false: A operand from fp32 V, reg-staged + converted
// ---------------------------------------------------------------------------
template <bool PRECONV>
__global__ __launch_bounds__(256) void k_scores(
    const float* __restrict__ Vf, const __bf16* __restrict__ Vb,
    const __bf16* __restrict__ UwT, const float* __restrict__ whp,
    const float* __restrict__ vw, float* __restrict__ e_part)
{
    __shared__ __align__(16) __bf16 As[BM][BKK];   // 16 KB, linear (gload_lds)
    __shared__ __align__(16) __bf16 Bs[BN][BKK];   // 16 KB, linear (gload_lds)
    __shared__ float red[2][BM];

    int mtile = blockIdx.x;       // 0..195
    int cc    = blockIdx.y;       // 0..3
    int m0 = mtile * BM;
    int c0 = cc * BN;
    int t    = threadIdx.x;
    int lane = t & 63;
    int wave = t >> 6;            // 0..3
    int wr = wave >> 1;           // 0..1 (row half: 64 rows)
    int wc = wave & 1;            // 0..1 (col half: 64 cols)

    f32x4 acc[4][4];
#pragma unroll
    for (int i = 0; i < 4; ++i)
#pragma unroll
        for (int j = 0; j < 4; ++j) acc[i][j] = (f32x4){0.f, 0.f, 0.f, 0.f};

    // ---- staging addresses ----
    // gload_lds pattern: wave w, round i covers rows [w*32 + i*8, +8), each
    // lane moves 16B; LDS dest = base(w,i) + lane*16 (linear layout required).
    int lr  = lane >> 3;          // 0..7
    int lcB = (lane & 7) * 8;     // bf16 elem offset within row
    const __bf16* Ag = PRECONV ? (Vb + (size_t)(m0 + wave * 32 + lr) * VDIM + lcB) : nullptr;
    const __bf16* Bg = UwT + (size_t)(c0 + wave * 32 + lr) * VDIM + lcB;
    __bf16* Al = &As[wave * 32 + lr][lcB];
    __bf16* Bl = &Bs[wave * 32 + lr][lcB];

    // fallback A staging (fp32 -> bf16 in regs)
    int ra = t >> 1;              // 0..127
    int ka = (t & 1) * 32;        // 0 or 32 floats
    const float* Af = PRECONV ? nullptr : (Vf + (size_t)(m0 + ra) * VDIM + ka);

    int lcol  = lane & 15;
    int lgrp8 = (lane >> 4) * 8;

    for (int k0 = 0; k0 < VDIM; k0 += BKK) {
        __syncthreads();
        if (PRECONV) {
#pragma unroll
            for (int i = 0; i < 4; ++i) {
                gload_lds16(Ag + k0 + (size_t)i * 8 * VDIM, Al + i * 512);
                gload_lds16(Bg + k0 + (size_t)i * 8 * VDIM, Bl + i * 512);
            }
        } else {
#pragma unroll
            for (int i = 0; i < 4; ++i)
                gload_lds16(Bg + k0 + (size_t)i * 8 * VDIM, Bl + i * 512);
            const float4* src = reinterpret_cast<const float4*>(Af + k0);
#pragma unroll
            for (int i = 0; i < 4; ++i) {
                float4 x = src[2 * i];
                float4 y = src[2 * i + 1];
                bf16x8 w;
                w[0] = (__bf16)x.x; w[1] = (__bf16)x.y; w[2] = (__bf16)x.z; w[3] = (__bf16)x.w;
                w[4] = (__bf16)y.x; w[5] = (__bf16)y.y; w[6] = (__bf16)y.z; w[7] = (__bf16)y.w;
                *reinterpret_cast<bf16x8*>(&As[ra][ka + 8 * i]) = w;
            }
        }
        __syncthreads();

        int arow_base = wr * 64;
        int bcol_base = wc * 64;
#pragma unroll
        for (int ks = 0; ks < 2; ++ks) {
            int kofs = ks * 32 + lgrp8;
            bf16x8 af[4], bfr[4];
#pragma unroll
            for (int i = 0; i < 4; ++i)
                af[i] = *reinterpret_cast<const bf16x8*>(&As[arow_base + i * 16 + lcol][kofs]);
#pragma unroll
            for (int j = 0; j < 4; ++j)
                bfr[j] = *reinterpret_cast<const bf16x8*>(&Bs[bcol_base + j * 16 + lcol][kofs]);
#pragma unroll
            for (int i = 0; i < 4; ++i)
#pragma unroll
                for (int j = 0; j < 4; ++j)
                    acc[i][j] = __builtin_amdgcn_mfma_f32_16x16x32_bf16(af[i], bfr[j], acc[i][j], 0, 0, 0);
        }
    }

    // ---- epilogue: rowsum over this block's 128 cols ----
    int lrow4 = (lane >> 4) * 4;
    float rowsum[4][4];
#pragma unroll
    for (int i = 0; i < 4; ++i)
#pragma unroll
        for (int r = 0; r < 4; ++r) rowsum[i][r] = 0.f;

#pragma unroll
    for (int j = 0; j < 4; ++j) {
        int col = c0 + wc * 64 + j * 16 + lcol;
        float vwv = vw[col];
#pragma unroll
        for (int i = 0; i < 4; ++i) {
#pragma unroll
            for (int r = 0; r < 4; ++r) {
                int m = m0 + wr * 64 + i * 16 + lrow4 + r;
                int b = m / N_;
                float x = acc[i][j][r] + whp[(size_t)b * ATT + col];
                rowsum[i][r] += fast_tanh(x) * vwv;
            }
        }
    }
#pragma unroll
    for (int i = 0; i < 4; ++i) {
#pragma unroll
        for (int r = 0; r < 4; ++r) {
            float v = rowsum[i][r];
            v += __shfl_xor(v, 1);
            v += __shfl_xor(v, 2);
            v += __shfl_xor(v, 4);
            v += __shfl_xor(v, 8);
            if (lcol == 0)
                red[wc][wr * 64 + i * 16 + lrow4 + r] = v;
        }
    }
    __syncthreads();
    if (t < BM)
        e_part[(size_t)cc * M_TOT + m0 + t] = red[0][t] + red[1][t];
}

// ---------------------------------------------------------------------------
// Kernel S: softmax over N=196 per batch; writes a -> d_out tail
// ---------------------------------------------------------------------------
__global__ void k_softmax(const float* __restrict__ e_part, const float* __restrict__ vb,
                          float* __restrict__ a_out) {
    int b = blockIdx.x;
    int t = threadIdx.x;  // 256
    __shared__ float sm[256];
    float ev = 0.f;
    float e  = -1e30f;
    if (t < N_) {
        int m = b * N_ + t;
        ev = e_part[m] + e_part[M_TOT + m] + e_part[2 * M_TOT + m] + e_part[3 * M_TOT + m] + vb[0];
        e = ev;
    }
    sm[t] = e;
    __syncthreads();
    for (int s = 128; s > 0; s >>= 1) {
        if (t < s) sm[t] = fmaxf(sm[t], sm[t + s]);
        __syncthreads();
    }
    float mx = sm[0];
    __syncthreads();
    float ex = (t < N_) ? __expf(ev - mx) : 0.f;
    sm[t] = ex;
    __syncthreads();
    for (int s = 128; s > 0; s >>= 1) {
        if (t < s) sm[t] += sm[t + s];
        __syncthreads();
    }
    float inv = 1.f / sm[0];
    if (t < N_) a_out[(size_t)b * N_ + t] = ex * inv;
}

// ---------------------------------------------------------------------------
// Kernel C: ctx[b][v] = sum_n a[b][n] * V[b][n][v]
// ---------------------------------------------------------------------------
__global__ void k_ctx_bf(const __bf16* __restrict__ Vb, const float* __restrict__ a,
                         float* __restrict__ ctx) {
    int b  = blockIdx.x;   // 128
    int ch = blockIdx.y;   // 4 chunks of 512 cols
    int t  = threadIdx.x;  // 128
    __shared__ float as_[N_];
    for (int i = t; i < N_; i += 128) as_[i] = a[(size_t)b * N_ + i];
    __syncthreads();
    int col = ch * 512 + t * 4;
    const __bf16* Vp = Vb + (size_t)b * N_ * VDIM + col;
    f32x4 accv = {0.f, 0.f, 0.f, 0.f};
    for (int n = 0; n < N_; ++n) {
        bf16x4 v = *reinterpret_cast<const bf16x4*>(Vp + (size_t)n * VDIM);
        float an = as_[n];
        accv.x += an * (float)v[0];
        accv.y += an * (float)v[1];
        accv.z += an * (float)v[2];
        accv.w += an * (float)v[3];
    }
    *reinterpret_cast<f32x4*>(ctx + (size_t)b * VDIM + col) = accv;
}

__global__ void k_ctx_f32(const float* __restrict__ V, const float* __restrict__ a,
                          float* __restrict__ ctx) {
    int b  = blockIdx.x;
    int ch = blockIdx.y;
    int t  = threadIdx.x;  // 128
    __shared__ float as_[N_];
    for (int i = t; i < N_; i += 128) as_[i] = a[(size_t)b * N_ + i];
    __syncthreads();
    int col = ch * 512 + t * 4;
    const f32x4* Vp = reinterpret_cast<const f32x4*>(V + (size_t)b * N_ * VDIM + col);
    f32x4 accv = {0.f, 0.f, 0.f, 0.f};
    for (int n = 0; n < N_; ++n)
        accv += as_[n] * Vp[(size_t)n * (VDIM / 4)];
    *reinterpret_cast<f32x4*>(ctx + (size_t)b * VDIM + col) = accv;
}

// ---------------------------------------------------------------------------
extern "C" void kernel_launch(void* const* d_in, const int* in_sizes, int n_in,
                              void* d_out, int out_size, void* d_ws, size_t ws_size,
                              hipStream_t stream) {
    const float* h  = (const float*)d_in[0];
    const float* V  = (const float*)d_in[1];
    const float* Ww = (const float*)d_in[2];
    const float* Wb = (const float*)d_in[3];
    const float* Uw = (const float*)d_in[4];
    const float* Ub = (const float*)d_in[5];
    const float* vw = (const float*)d_in[6];
    const float* vb = (const float*)d_in[7];

    float* out     = (float*)d_out;
    float* ctx_out = out;                        // B*VDIM floats
    float* a_out   = out + (size_t)B_ * VDIM;    // B*N floats

    const size_t vb_bytes = (size_t)B_ * N_ * VDIM * sizeof(__bf16);  // ~103 MB
    const size_t tail     = 2u * 1024 * 1024 + 256 * 1024 + (size_t)4 * M_TOT * 4 + 4096;
    bool preconv = ws_size >= vb_bytes + tail;

    char*   ws   = (char*)d_ws;
    __bf16* Vb   = (__bf16*)ws;
    char*   rest = ws + (preconv ? vb_bytes : 0);
    __bf16* UwT   = (__bf16*)rest;
    float*  whp   = (float*)(rest + 2u * 1024 * 1024);
    float*  e_prt = (float*)(rest + 2u * 1024 * 1024 + 256 * 1024);

    if (preconv) {
        int n8 = (B_ * N_ * VDIM) / 8;
        k_conv<<<2048, 256, 0, stream>>>(V, Vb, n8);
    }
    k_transpose<<<dim3(VDIM / 64, ATT / 64), 256, 0, stream>>>(Uw, UwT);
    k_wh<<<dim3(B_), 256, 0, stream>>>(h, Ww, Wb, Ub, whp);
    if (preconv)
        k_scores<true><<<dim3(M_TOT / BM, ATT / BN), 256, 0, stream>>>(V, Vb, UwT, whp, vw, e_prt);
    else
        k_scores<false><<<dim3(M_TOT / BM, ATT / BN), 256, 0, stream>>>(V, Vb, UwT, whp, vw, e_prt);
    k_softmax<<<dim3(B_), 256, 0, stream>>>(e_prt, vb, a_out);
    if (preconv)
        k_ctx_bf<<<dim3(B_, 4), 128, 0, stream>>>(Vb, a_out, ctx_out);
    else
        k_ctx_f32<<<dim3(B_, 4), 128, 0, stream>>>(V, a_out, ctx_out);
}

// Round 3
// 177.811 us; speedup vs baseline: 1.2044x; 1.2044x over previous
//
#include <hip/hip_runtime.h>
#include <hip/hip_bf16.h>

#define B_    128
#define N_    196
#define HDIM  512
#define VDIM  2048
#define ATT   512
#define M_TOT (B_ * N_)   // 25088

#define BM  128    // rows per GEMM block
#define BKK 64     // K step (64 bf16 = 128B row = 8 chunks of 16B)
#define BN  128    // ATT cols per GEMM block (4 chunks)
#define NT  (VDIM / BKK)   // 32 K-steps

typedef float  f32x4  __attribute__((ext_vector_type(4)));
typedef __bf16 bf16x8 __attribute__((ext_vector_type(8)));

__device__ __forceinline__ void gload_lds16(const void* g, void* l) {
    __builtin_amdgcn_global_load_lds(
        (const __attribute__((address_space(1))) void*)g,
        (__attribute__((address_space(3))) void*)l, 16, 0, 0);
}

__device__ __forceinline__ float fast_tanh(float x) {
    float ax = fabsf(x);
    float e  = __expf(-2.f * ax);          // in (0,1], no overflow
    float t  = (1.f - e) / (1.f + e);
    return copysignf(t, x);
}

// ---------------------------------------------------------------------------
// Kernel CV: V fp32 -> bf16 (streaming)
// ---------------------------------------------------------------------------
__global__ void k_conv(const float* __restrict__ V, __bf16* __restrict__ Vb, int n8) {
    int idx    = blockIdx.x * blockDim.x + threadIdx.x;
    int stride = gridDim.x * blockDim.x;
    for (int i = idx; i < n8; i += stride) {
        const float4* s = reinterpret_cast<const float4*>(V + (size_t)i * 8);
        float4 x = s[0], y = s[1];
        bf16x8 w;
        w[0] = (__bf16)x.x; w[1] = (__bf16)x.y; w[2] = (__bf16)x.z; w[3] = (__bf16)x.w;
        w[4] = (__bf16)y.x; w[5] = (__bf16)y.y; w[6] = (__bf16)y.z; w[7] = (__bf16)y.w;
        reinterpret_cast<bf16x8*>(Vb)[i] = w;
    }
}

// ---------------------------------------------------------------------------
// Kernel T: Uw [VDIM][ATT] f32 -> UwT [ATT][VDIM] bf16
// ---------------------------------------------------------------------------
__global__ void k_transpose(const float* __restrict__ Uw, __bf16* __restrict__ UwT) {
    __shared__ __bf16 st[64][65];
    int k0 = blockIdx.x * 64;
    int c0 = blockIdx.y * 64;
    int t  = threadIdx.x;  // 256
#pragma unroll
    for (int i = 0; i < 16; ++i) {
        int lin = i * 256 + t;
        int kk = lin >> 6, cc = lin & 63;
        st[kk][cc] = (__bf16)Uw[(size_t)(k0 + kk) * ATT + c0 + cc];
    }
    __syncthreads();
#pragma unroll
    for (int i = 0; i < 16; ++i) {
        int lin = i * 256 + t;
        int cc = lin >> 6, kk = lin & 63;
        UwT[(size_t)(c0 + cc) * VDIM + k0 + kk] = st[kk][cc];
    }
}

// ---------------------------------------------------------------------------
// Kernel W: whp[b][a] = h[b] @ Ww[:,a] + Wb[a] + Ub[a]
// ---------------------------------------------------------------------------
__global__ void k_wh(const float* __restrict__ h, const float* __restrict__ Ww,
                     const float* __restrict__ Wb, const float* __restrict__ Ub,
                     float* __restrict__ whp) {
    __shared__ float hs[HDIM];
    int b = blockIdx.x;
    int t = threadIdx.x;  // 256
    hs[t]       = h[(size_t)b * HDIM + t];
    hs[t + 256] = h[(size_t)b * HDIM + t + 256];
    __syncthreads();
    float acc0 = 0.f, acc1 = 0.f;
    for (int k = 0; k < HDIM; ++k) {
        float hv = hs[k];
        acc0 += hv * Ww[(size_t)k * ATT + t];
        acc1 += hv * Ww[(size_t)k * ATT + t + 256];
    }
    whp[(size_t)b * ATT + t]       = acc0 + Wb[t] + Ub[t];
    whp[(size_t)b * ATT + t + 256] = acc1 + Wb[t + 256] + Ub[t + 256];
}

// ---------------------------------------------------------------------------
// Kernel G: 128x128 tile, BK=64, 4 waves. 2-phase double-buffered LDS with
// T2 XOR-swizzle (pre-swizzled global source, linear gload_lds dest,
// swizzled ds_read). Epilogue: e_part[cc][m] = sum_cols tanh(acc+whp)*vw.
// Grid: 1D 784 blocks, XCD-bijective swizzle -> (mtile, cc).
// ---------------------------------------------------------------------------
template <bool PRECONV>
__global__ __launch_bounds__(256, 2) void k_scores(
    const float* __restrict__ Vf, const __bf16* __restrict__ Vb,
    const __bf16* __restrict__ UwT, const float* __restrict__ whp,
    const float* __restrict__ vw, float* __restrict__ e_part)
{
    __shared__ __align__(16) __bf16 As[2][BM][BKK];   // 2 x 16 KB
    __shared__ __align__(16) __bf16 Bs[2][BN][BKK];   // 2 x 16 KB
    __shared__ float red[2][BM];

    // XCD-bijective swizzle: 784 blocks, 8 XCDs, 98 per XCD (784%8==0).
    int bid = blockIdx.x;
    int lid = (bid & 7) * (784 / 8) + (bid >> 3);
    int mtile = lid >> 2;         // 0..195
    int cc    = lid & 3;          // 0..3
    int m0 = mtile * BM;
    int c0 = cc * BN;
    int t    = threadIdx.x;
    int lane = t & 63;
    int wave = t >> 6;            // 0..3
    int wr = wave >> 1;           // row half (64 rows)
    int wc = wave & 1;            // col half (64 cols)

    f32x4 acc[4][4];
#pragma unroll
    for (int i = 0; i < 4; ++i)
#pragma unroll
        for (int j = 0; j < 4; ++j) acc[i][j] = (f32x4){0.f, 0.f, 0.f, 0.f};

    // ---- staging addresses (gload_lds: linear dest, swizzled source) ----
    // wave w, round i covers rows [w*32+i*8, +8); lane -> (row=lr, chunk=lane&7).
    // LDS[row][c] must hold global chunk (c ^ (row&7)); dest is linear, so
    // the SOURCE chunk for lane = (lane&7) ^ (lr&7).
    int lr  = lane >> 3;                         // 0..7
    int csw = ((lane & 7) ^ (lr & 7)) * 8;       // swizzled source elem offset
    const __bf16* AgS = PRECONV ? (Vb + (size_t)(m0 + wave * 32 + lr) * VDIM + csw) : nullptr;
    const __bf16* BgS = UwT + (size_t)(c0 + wave * 32 + lr) * VDIM + csw;
    __bf16* Al0 = &As[0][wave * 32 + lr][(lane & 7) * 8];  // linear dest
    __bf16* Bl0 = &Bs[0][wave * 32 + lr][(lane & 7) * 8];

    // fallback A staging (fp32 -> bf16 regs -> swizzled ds_write)
    int ra = t >> 1;              // 0..127
    int ka = (t & 1) * 32;        // 0 or 32 (floats)
    const float* Af = PRECONV ? nullptr : (Vf + (size_t)(m0 + ra) * VDIM + ka);

    int lcol = lane & 15;
    int lg4  = lane >> 4;         // 0..3

#define STAGE(buf, kt)                                                          \
    do {                                                                        \
        int kk0 = (kt) * BKK;                                                   \
        if (PRECONV) {                                                          \
            _Pragma("unroll")                                                   \
            for (int i = 0; i < 4; ++i) {                                       \
                gload_lds16(AgS + kk0 + (size_t)i * 8 * VDIM,                   \
                            Al0 + (buf) * (BM * BKK) + i * 8 * BKK);            \
                gload_lds16(BgS + kk0 + (size_t)i * 8 * VDIM,                   \
                            Bl0 + (buf) * (BN * BKK) + i * 8 * BKK);            \
            }                                                                   \
        } else {                                                                \
            _Pragma("unroll")                                                   \
            for (int i = 0; i < 4; ++i)                                         \
                gload_lds16(BgS + kk0 + (size_t)i * 8 * VDIM,                   \
                            Bl0 + (buf) * (BN * BKK) + i * 8 * BKK);            \
            const float4* src = reinterpret_cast<const float4*>(Af + kk0);      \
            _Pragma("unroll")                                                   \
            for (int i = 0; i < 4; ++i) {                                       \
                float4 x = src[2 * i];                                          \
                float4 y = src[2 * i + 1];                                      \
                bf16x8 w;                                                       \
                w[0] = (__bf16)x.x; w[1] = (__bf16)x.y;                         \
                w[2] = (__bf16)x.z; w[3] = (__bf16)x.w;                         \
                w[4] = (__bf16)y.x; w[5] = (__bf16)y.y;                         \
                w[6] = (__bf16)y.z; w[7] = (__bf16)y.w;                         \
                int ch = (((t & 1) * 4 + i) ^ (ra & 7)) * 8;                    \
                *reinterpret_cast<bf16x8*>(&As[buf][ra][ch]) = w;               \
            }                                                                   \
        }                                                                       \
    } while (0)

    int arow_base = wr * 64;
    int bcol_base = wc * 64;

    STAGE(0, 0);
    __syncthreads();   // vmcnt(0)+lgkmcnt(0) drain + barrier

    for (int kt = 0; kt < NT; ++kt) {
        int buf = kt & 1;
        if (kt + 1 < NT) STAGE(buf ^ 1, kt + 1);   // prefetch next tile

        // compute current tile (swizzled reads)
#pragma unroll
        for (int ks = 0; ks < 2; ++ks) {
            bf16x8 af[4], bfr[4];
#pragma unroll
            for (int i = 0; i < 4; ++i) {
                int row = arow_base + i * 16 + lcol;
                int ch  = ((ks * 4 + lg4) ^ (row & 7)) * 8;
                af[i] = *reinterpret_cast<const bf16x8*>(&As[buf][row][ch]);
            }
#pragma unroll
            for (int j = 0; j < 4; ++j) {
                int row = bcol_base + j * 16 + lcol;
                int ch  = ((ks * 4 + lg4) ^ (row & 7)) * 8;
                bfr[j] = *reinterpret_cast<const bf16x8*>(&Bs[buf][row][ch]);
            }
            __builtin_amdgcn_s_setprio(1);
#pragma unroll
            for (int i = 0; i < 4; ++i)
#pragma unroll
                for (int j = 0; j < 4; ++j)
                    acc[i][j] = __builtin_amdgcn_mfma_f32_16x16x32_bf16(af[i], bfr[j], acc[i][j], 0, 0, 0);
            __builtin_amdgcn_s_setprio(0);
        }
        __syncthreads();   // drains this iter's prefetch (vmcnt0) + barrier
    }
#undef STAGE

    // ---- epilogue: rowsum over this block's 128 cols ----
    int lrow4 = lg4 * 4;
    float rowsum[4][4];
#pragma unroll
    for (int i = 0; i < 4; ++i)
#pragma unroll
        for (int r = 0; r < 4; ++r) rowsum[i][r] = 0.f;

#pragma unroll
    for (int j = 0; j < 4; ++j) {
        int col = c0 + wc * 64 + j * 16 + lcol;
        float vwv = vw[col];
#pragma unroll
        for (int i = 0; i < 4; ++i) {
#pragma unroll
            for (int r = 0; r < 4; ++r) {
                int m = m0 + wr * 64 + i * 16 + lrow4 + r;
                int b = m / N_;
                float x = acc[i][j][r] + whp[(size_t)b * ATT + col];
                rowsum[i][r] += fast_tanh(x) * vwv;
            }
        }
    }
#pragma unroll
    for (int i = 0; i < 4; ++i) {
#pragma unroll
        for (int r = 0; r < 4; ++r) {
            float v = rowsum[i][r];
            v += __shfl_xor(v, 1);
            v += __shfl_xor(v, 2);
            v += __shfl_xor(v, 4);
            v += __shfl_xor(v, 8);
            if (lcol == 0)
                red[wc][wr * 64 + i * 16 + lrow4 + r] = v;
        }
    }
    __syncthreads();
    if (t < BM)
        e_part[(size_t)cc * M_TOT + m0 + t] = red[0][t] + red[1][t];
}

// ---------------------------------------------------------------------------
// Kernel S: softmax over N=196 per batch; writes a -> d_out tail
// ---------------------------------------------------------------------------
__global__ void k_softmax(const float* __restrict__ e_part, const float* __restrict__ vb,
                          float* __restrict__ a_out) {
    int b = blockIdx.x;
    int t = threadIdx.x;  // 256
    __shared__ float sm[256];
    float ev = 0.f;
    float e  = -1e30f;
    if (t < N_) {
        int m = b * N_ + t;
        ev = e_part[m] + e_part[M_TOT + m] + e_part[2 * M_TOT + m] + e_part[3 * M_TOT + m] + vb[0];
        e = ev;
    }
    sm[t] = e;
    __syncthreads();
    for (int s = 128; s > 0; s >>= 1) {
        if (t < s) sm[t] = fmaxf(sm[t], sm[t + s]);
        __syncthreads();
    }
    float mx = sm[0];
    __syncthreads();
    float ex = (t < N_) ? __expf(ev - mx) : 0.f;
    sm[t] = ex;
    __syncthreads();
    for (int s = 128; s > 0; s >>= 1) {
        if (t < s) sm[t] += sm[t + s];
        __syncthreads();
    }
    float inv = 1.f / sm[0];
    if (t < N_) a_out[(size_t)b * N_ + t] = ex * inv;
}

// ---------------------------------------------------------------------------
// Kernel C: ctx[b][v] = sum_n a[b][n] * V[b][n][v]
// ---------------------------------------------------------------------------
__global__ void k_ctx_bf(const __bf16* __restrict__ Vb, const float* __restrict__ a,
                         float* __restrict__ ctx) {
    int b  = blockIdx.x;   // 128
    int ch = blockIdx.y;   // 2 chunks of 1024 cols
    int t  = threadIdx.x;  // 128
    __shared__ float as_[N_];
    for (int i = t; i < N_; i += 128) as_[i] = a[(size_t)b * N_ + i];
    __syncthreads();
    int col = ch * 1024 + t * 8;
    const __bf16* Vp = Vb + (size_t)b * N_ * VDIM + col;
    float av[8] = {0.f, 0.f, 0.f, 0.f, 0.f, 0.f, 0.f, 0.f};
    for (int n = 0; n < N_; ++n) {
        bf16x8 v = *reinterpret_cast<const bf16x8*>(Vp + (size_t)n * VDIM);
        float an = as_[n];
#pragma unroll
        for (int j = 0; j < 8; ++j) av[j] += an * (float)v[j];
    }
    f32x4 lo = {av[0], av[1], av[2], av[3]};
    f32x4 hi = {av[4], av[5], av[6], av[7]};
    f32x4* dst = reinterpret_cast<f32x4*>(ctx + (size_t)b * VDIM + col);
    dst[0] = lo;
    dst[1] = hi;
}

__global__ void k_ctx_f32(const float* __restrict__ V, const float* __restrict__ a,
                          float* __restrict__ ctx) {
    int b  = blockIdx.x;
    int ch = blockIdx.y;
    int t  = threadIdx.x;  // 128
    __shared__ float as_[N_];
    for (int i = t; i < N_; i += 128) as_[i] = a[(size_t)b * N_ + i];
    __syncthreads();
    int col = ch * 512 + t * 4;
    const f32x4* Vp = reinterpret_cast<const f32x4*>(V + (size_t)b * N_ * VDIM + col);
    f32x4 accv = {0.f, 0.f, 0.f, 0.f};
    for (int n = 0; n < N_; ++n)
        accv += as_[n] * Vp[(size_t)n * (VDIM / 4)];
    *reinterpret_cast<f32x4*>(ctx + (size_t)b * VDIM + col) = accv;
}

// ---------------------------------------------------------------------------
extern "C" void kernel_launch(void* const* d_in, const int* in_sizes, int n_in,
                              void* d_out, int out_size, void* d_ws, size_t ws_size,
                              hipStream_t stream) {
    const float* h  = (const float*)d_in[0];
    const float* V  = (const float*)d_in[1];
    const float* Ww = (const float*)d_in[2];
    const float* Wb = (const float*)d_in[3];
    const float* Uw = (const float*)d_in[4];
    const float* Ub = (const float*)d_in[5];
    const float* vw = (const float*)d_in[6];
    const float* vb = (const float*)d_in[7];

    float* out     = (float*)d_out;
    float* ctx_out = out;                        // B*VDIM floats
    float* a_out   = out + (size_t)B_ * VDIM;    // B*N floats

    const size_t vb_bytes = (size_t)B_ * N_ * VDIM * sizeof(__bf16);  // ~103 MB
    const size_t tail     = 2u * 1024 * 1024 + 256 * 1024 + (size_t)4 * M_TOT * 4 + 4096;
    bool preconv = ws_size >= vb_bytes + tail;

    char*   ws   = (char*)d_ws;
    __bf16* Vb   = (__bf16*)ws;
    char*   rest = ws + (preconv ? vb_bytes : 0);
    __bf16* UwT   = (__bf16*)rest;
    float*  whp   = (float*)(rest + 2u * 1024 * 1024);
    float*  e_prt = (float*)(rest + 2u * 1024 * 1024 + 256 * 1024);

    if (preconv) {
        int n8 = (B_ * N_ * VDIM) / 8;
        k_conv<<<2048, 256, 0, stream>>>(V, Vb, n8);
    }
    k_transpose<<<dim3(VDIM / 64, ATT / 64), 256, 0, stream>>>(Uw, UwT);
    k_wh<<<dim3(B_), 256, 0, stream>>>(h, Ww, Wb, Ub, whp);
    if (preconv)
        k_scores<true><<<dim3((M_TOT / BM) * (ATT / BN)), 256, 0, stream>>>(V, Vb, UwT, whp, vw, e_prt);
    else
        k_scores<false><<<dim3((M_TOT / BM) * (ATT / BN)), 256, 0, stream>>>(V, Vb, UwT, whp, vw, e_prt);
    k_softmax<<<dim3(B_), 256, 0, stream>>>(e_prt, vb, a_out);
    if (preconv)
        k_ctx_bf<<<dim3(B_, 2), 128, 0, stream>>>(Vb, a_out, ctx_out);
    else
        k_ctx_f32<<<dim3(B_, 4), 128, 0, stream>>>(V, a_out, ctx_out);
}